// Round 1
// baseline (5691.251 us; speedup 1.0000x reference)
//
#include <hip/hip_runtime.h>

#define N_NODES 50000
#define E_EDGES 800000
#define D 256
#define L 128

__global__ __launch_bounds__(256) void zero_f4(float4* __restrict__ p, int n4) {
    int i = blockIdx.x * 256 + threadIdx.x;
    if (i < n4) p[i] = make_float4(0.f, 0.f, 0.f, 0.f);
}

__global__ __launch_bounds__(256) void deg_count(const int* __restrict__ dst,
                                                 float* __restrict__ deg) {
    int e = blockIdx.x * 256 + threadIdx.x;
    if (e < E_EDGES) atomicAdd(&deg[dst[e]], 1.0f);
}

__global__ __launch_bounds__(256) void deg_fin(float* __restrict__ dinv) {
    int i = blockIdx.x * 256 + threadIdx.x;
    if (i < N_NODES) dinv[i] = rsqrtf(dinv[i] + 1.0f);
}

// C[M,·] = A[M,256] @ B[256,·] (+bias). 64x64 tile, 4x4 microtile, K=256 fixed.
__global__ __launch_bounds__(256) void gemm_k256(
    const float* __restrict__ A, const float* __restrict__ B, int ldb,
    const float* __restrict__ bias, float* __restrict__ C, int ldc, int M)
{
    __shared__ float As[16][68];   // [k][m], pad 68 keeps float4 reads aligned, breaks conflicts
    __shared__ float Bs[16][64];   // [k][n]
    const int t  = threadIdx.x;
    const int tx = t & 15, ty = t >> 4;
    const int row0 = blockIdx.x * 64, col0 = blockIdx.y * 64;
    const int lr = t >> 2, lc = (t & 3) << 2;   // A-tile load: row, k-offset
    const int br = t >> 4, bc = (t & 15) << 2;  // B-tile load: k-row, col
    int arow = row0 + lr; if (arow >= M) arow = M - 1;  // clamp; garbage rows never stored
    const float* Ap = A + arow * 256 + lc;
    const float* Bp = B + br * ldb + col0 + bc;
    float acc[4][4] = {};
    for (int kk = 0; kk < 256; kk += 16) {
        float4 av = *(const float4*)(Ap + kk);
        float4 bv = *(const float4*)(Bp + kk * ldb);
        __syncthreads();
        As[lc + 0][lr] = av.x; As[lc + 1][lr] = av.y;
        As[lc + 2][lr] = av.z; As[lc + 3][lr] = av.w;
        *(float4*)&Bs[br][bc] = bv;
        __syncthreads();
#pragma unroll
        for (int k = 0; k < 16; ++k) {
            float4 a4 = *(const float4*)&As[k][ty * 4];
            float4 b4 = *(const float4*)&Bs[k][tx * 4];
            float am[4] = {a4.x, a4.y, a4.z, a4.w};
            float bn[4] = {b4.x, b4.y, b4.z, b4.w};
#pragma unroll
            for (int i = 0; i < 4; ++i)
#pragma unroll
                for (int j = 0; j < 4; ++j)
                    acc[i][j] = fmaf(am[i], bn[j], acc[i][j]);
        }
    }
    float4 bb = make_float4(0.f, 0.f, 0.f, 0.f);
    if (bias) bb = *(const float4*)&bias[col0 + tx * 4];
#pragma unroll
    for (int i = 0; i < 4; ++i) {
        int r = row0 + ty * 4 + i;
        if (r < M) {
            float4 o;
            o.x = acc[i][0] + bb.x; o.y = acc[i][1] + bb.y;
            o.z = acc[i][2] + bb.z; o.w = acc[i][3] + bb.w;
            *(float4*)&C[r * ldc + col0 + tx * 4] = o;
        }
    }
}

// One edge per 64-lane group; each lane handles 4 contiguous cols (float4 gather, 4 atomics).
__global__ __launch_bounds__(256) void scatter_add(
    const float* __restrict__ Hs, float* __restrict__ Acc,
    const int* __restrict__ src, const int* __restrict__ dst,
    const float* __restrict__ dinv)
{
    int e = blockIdx.x * 4 + (threadIdx.x >> 6);
    if (e >= E_EDGES) return;
    int lane = threadIdx.x & 63;
    int s = src[e], d = dst[e];
    float w = dinv[s] * dinv[d];
    float4 v = *(const float4*)&Hs[s * D + lane * 4];
    float* o = &Acc[d * D + lane * 4];
    atomicAdd(o + 0, v.x * w);
    atomicAdd(o + 1, v.y * w);
    atomicAdd(o + 2, v.z * w);
    atomicAdd(o + 3, v.w * w);
}

// Z = relu(AGG + H*dinv^2 + b1), in place over AGG
__global__ __launch_bounds__(256) void finalize_relu(
    float* __restrict__ Z, const float* __restrict__ H,
    const float* __restrict__ dinv, const float* __restrict__ b1)
{
    int i = blockIdx.x * 256 + threadIdx.x;  // over N*64 float4 groups
    if (i >= N_NODES * 64) return;
    int node = i >> 6, c4 = (i & 63) << 2;
    float di = dinv[node], sl = di * di;
    float4 a = *(const float4*)&Z[node * D + c4];
    float4 h = *(const float4*)&H[node * D + c4];
    float4 b = *(const float4*)&b1[c4];
    float4 r;
    r.x = fmaxf(fmaf(h.x, sl, a.x) + b.x, 0.f);
    r.y = fmaxf(fmaf(h.y, sl, a.y) + b.y, 0.f);
    r.z = fmaxf(fmaf(h.z, sl, a.z) + b.z, 0.f);
    r.w = fmaxf(fmaf(h.w, sl, a.w) + b.w, 0.f);
    *(float4*)&Z[node * D + c4] = r;
}

// Y += Z*dinv^2 (self-loop term of layer-2 aggregation; bias handled in GEMM epilogue)
__global__ __launch_bounds__(256) void finalize_self(
    float* __restrict__ Y, const float* __restrict__ Z,
    const float* __restrict__ dinv)
{
    int i = blockIdx.x * 256 + threadIdx.x;
    if (i >= N_NODES * 64) return;
    int node = i >> 6, c4 = (i & 63) << 2;
    float di = dinv[node], sl = di * di;
    float4 y = *(const float4*)&Y[node * D + c4];
    float4 z = *(const float4*)&Z[node * D + c4];
    y.x = fmaf(z.x, sl, y.x);
    y.y = fmaf(z.y, sl, y.y);
    y.z = fmaf(z.z, sl, y.z);
    y.w = fmaf(z.w, sl, y.w);
    *(float4*)&Y[node * D + c4] = y;
}

extern "C" void kernel_launch(void* const* d_in, const int* in_sizes, int n_in,
                              void* d_out, int out_size, void* d_ws, size_t ws_size,
                              hipStream_t stream) {
    const float* x   = (const float*)d_in[0];
    const int*   ei  = (const int*)d_in[1];   // [2, E] int32
    const float* W1  = (const float*)d_in[2];
    const float* b1  = (const float*)d_in[3];
    const float* Wmu = (const float*)d_in[4];
    const float* bmu = (const float*)d_in[5];
    const float* Wlv = (const float*)d_in[6];
    const float* blv = (const float*)d_in[7];
    const int* src = ei;
    const int* dst = ei + E_EDGES;

    float* H    = (float*)d_ws;          // [N,256]
    float* Z    = H + (size_t)N_NODES * D;  // AGG1 -> Z in place
    float* dinv = Z + (size_t)N_NODES * D;  // [N]
    float* Y    = H;                     // reuse H after finalize_relu
    float* mu   = (float*)d_out;
    float* lv   = mu + (size_t)N_NODES * L;

    const int elem_blocks = (N_NODES * 64) / 256;  // 12500

    // degrees
    zero_f4<<<(N_NODES / 4 + 255) / 256, 256, 0, stream>>>((float4*)dinv, N_NODES / 4);
    deg_count<<<(E_EDGES + 255) / 256, 256, 0, stream>>>(dst, dinv);
    deg_fin<<<(N_NODES + 255) / 256, 256, 0, stream>>>(dinv);

    // layer 1
    gemm_k256<<<dim3(782, 4), 256, 0, stream>>>(x, W1, D, nullptr, H, D, N_NODES);
    zero_f4<<<elem_blocks, 256, 0, stream>>>((float4*)Z, N_NODES * 64);
    scatter_add<<<E_EDGES / 4, 256, 0, stream>>>(H, Z, src, dst, dinv);
    finalize_relu<<<elem_blocks, 256, 0, stream>>>(Z, H, dinv, b1);

    // layer 2: Y = P @ Z once (aggregation commutes with the dense matmuls)
    zero_f4<<<elem_blocks, 256, 0, stream>>>((float4*)Y, N_NODES * 64);
    scatter_add<<<E_EDGES / 4, 256, 0, stream>>>(Z, Y, src, dst, dinv);
    finalize_self<<<elem_blocks, 256, 0, stream>>>(Y, Z, dinv);

    // heads
    gemm_k256<<<dim3(782, 2), 256, 0, stream>>>(Y, Wmu, L, bmu, mu, L, N_NODES);
    gemm_k256<<<dim3(782, 2), 256, 0, stream>>>(Y, Wlv, L, blv, lv, L, N_NODES);
}

// Round 2
// 644.885 us; speedup vs baseline: 8.8252x; 8.8252x over previous
//
#include <hip/hip_runtime.h>

#define N_NODES 50000
#define E_EDGES 800000
#define D 256
#define L 128

__global__ __launch_bounds__(256) void zero_i(int* __restrict__ p, int n) {
    int i = blockIdx.x * 256 + threadIdx.x;
    if (i < n) p[i] = 0;
}

__global__ __launch_bounds__(256) void deg_count(const int* __restrict__ dst,
                                                 int* __restrict__ deg) {
    int e = blockIdx.x * 256 + threadIdx.x;
    if (e < E_EDGES) atomicAdd(&deg[dst[e]], 1);
}

// single-block exclusive scan of deg[N] -> row_start[N+1]; wave-scan + cross-wave offsets
__global__ __launch_bounds__(1024) void scan_rows(const int* __restrict__ deg,
                                                  int* __restrict__ row_start) {
    __shared__ int wsum[16];
    __shared__ int wofs[17];
    __shared__ int carry_s;
    const int t = threadIdx.x, lane = t & 63, wid = t >> 6;
    if (t == 0) carry_s = 0;
    __syncthreads();
    for (int base = 0; base < N_NODES; base += 1024) {
        int idx = base + t;
        int v = (idx < N_NODES) ? deg[idx] : 0;
        int s = v;
#pragma unroll
        for (int off = 1; off < 64; off <<= 1) {
            int x = __shfl_up(s, off, 64);
            if (lane >= off) s += x;
        }
        if (lane == 63) wsum[wid] = s;
        __syncthreads();
        if (t == 0) {
            int a = 0;
#pragma unroll
            for (int i = 0; i < 16; ++i) { wofs[i] = a; a += wsum[i]; }
            wofs[16] = a;
        }
        __syncthreads();
        if (idx < N_NODES) row_start[idx] = carry_s + wofs[wid] + s - v;  // exclusive
        __syncthreads();
        if (t == 0) carry_s += wofs[16];
        __syncthreads();
    }
    if (t == 0) row_start[N_NODES] = carry_s;
}

__global__ __launch_bounds__(256) void deg_fin(const int* __restrict__ deg,
                                               float* __restrict__ dinv) {
    int i = blockIdx.x * 256 + threadIdx.x;
    if (i < N_NODES) dinv[i] = rsqrtf((float)deg[i] + 1.0f);
}

__global__ __launch_bounds__(256) void fill_csr(const int* __restrict__ src,
                                                const int* __restrict__ dst,
                                                const int* __restrict__ row_start,
                                                int* __restrict__ cursor,
                                                int* __restrict__ csr_src) {
    int e = blockIdx.x * 256 + threadIdx.x;
    if (e >= E_EDGES) return;
    int d = dst[e];
    int pos = atomicAdd(&cursor[d], 1);
    csr_src[row_start[d] + pos] = src[e];
}

// One wave per dst node: acc[256] in regs (float4/lane), loop in-edges, write once.
// Fuses self-loop term + optional bias + optional relu.
__global__ __launch_bounds__(256) void gather_csr(
    const float* __restrict__ Hs, float* __restrict__ Out,
    const int* __restrict__ row_start, const int* __restrict__ csr_src,
    const float* __restrict__ dinv, const float* __restrict__ bias, int do_relu)
{
    int node = blockIdx.x * 4 + (threadIdx.x >> 6);
    if (node >= N_NODES) return;
    int lane = threadIdx.x & 63;
    int beg = row_start[node], end = row_start[node + 1];
    float dn = dinv[node];
    float4 acc = make_float4(0.f, 0.f, 0.f, 0.f);
    int i = beg;
    for (; i + 1 < end; i += 2) {   // 2-way unroll: overlap the two dependent-load chains
        int s0 = csr_src[i], s1 = csr_src[i + 1];
        float w0 = dinv[s0] * dn, w1 = dinv[s1] * dn;
        float4 v0 = *(const float4*)&Hs[(size_t)s0 * D + lane * 4];
        float4 v1 = *(const float4*)&Hs[(size_t)s1 * D + lane * 4];
        acc.x = fmaf(v1.x, w1, fmaf(v0.x, w0, acc.x));
        acc.y = fmaf(v1.y, w1, fmaf(v0.y, w0, acc.y));
        acc.z = fmaf(v1.z, w1, fmaf(v0.z, w0, acc.z));
        acc.w = fmaf(v1.w, w1, fmaf(v0.w, w0, acc.w));
    }
    if (i < end) {
        int s0 = csr_src[i];
        float w0 = dinv[s0] * dn;
        float4 v0 = *(const float4*)&Hs[(size_t)s0 * D + lane * 4];
        acc.x = fmaf(v0.x, w0, acc.x);
        acc.y = fmaf(v0.y, w0, acc.y);
        acc.z = fmaf(v0.z, w0, acc.z);
        acc.w = fmaf(v0.w, w0, acc.w);
    }
    float sl = dn * dn;  // self-loop norm = 1/deg
    float4 h = *(const float4*)&Hs[(size_t)node * D + lane * 4];
    acc.x = fmaf(h.x, sl, acc.x);
    acc.y = fmaf(h.y, sl, acc.y);
    acc.z = fmaf(h.z, sl, acc.z);
    acc.w = fmaf(h.w, sl, acc.w);
    if (bias) {
        float4 b = *(const float4*)&bias[lane * 4];
        acc.x += b.x; acc.y += b.y; acc.z += b.z; acc.w += b.w;
    }
    if (do_relu) {
        acc.x = fmaxf(acc.x, 0.f); acc.y = fmaxf(acc.y, 0.f);
        acc.z = fmaxf(acc.z, 0.f); acc.w = fmaxf(acc.w, 0.f);
    }
    *(float4*)&Out[(size_t)node * D + lane * 4] = acc;
}

// C[M,·] = A[M,256] @ B[256,·] (+bias). 64x64 tile, 4x4 microtile, K=256 fixed.
__global__ __launch_bounds__(256) void gemm_k256(
    const float* __restrict__ A, const float* __restrict__ B, int ldb,
    const float* __restrict__ bias, float* __restrict__ C, int ldc, int M)
{
    __shared__ float As[16][68];
    __shared__ float Bs[16][64];
    const int t  = threadIdx.x;
    const int tx = t & 15, ty = t >> 4;
    const int row0 = blockIdx.x * 64, col0 = blockIdx.y * 64;
    const int lr = t >> 2, lc = (t & 3) << 2;
    const int br = t >> 4, bc = (t & 15) << 2;
    int arow = row0 + lr; if (arow >= M) arow = M - 1;
    const float* Ap = A + arow * 256 + lc;
    const float* Bp = B + br * ldb + col0 + bc;
    float acc[4][4] = {};
    for (int kk = 0; kk < 256; kk += 16) {
        float4 av = *(const float4*)(Ap + kk);
        float4 bv = *(const float4*)(Bp + kk * ldb);
        __syncthreads();
        As[lc + 0][lr] = av.x; As[lc + 1][lr] = av.y;
        As[lc + 2][lr] = av.z; As[lc + 3][lr] = av.w;
        *(float4*)&Bs[br][bc] = bv;
        __syncthreads();
#pragma unroll
        for (int k = 0; k < 16; ++k) {
            float4 a4 = *(const float4*)&As[k][ty * 4];
            float4 b4 = *(const float4*)&Bs[k][tx * 4];
            float am[4] = {a4.x, a4.y, a4.z, a4.w};
            float bn[4] = {b4.x, b4.y, b4.z, b4.w};
#pragma unroll
            for (int i = 0; i < 4; ++i)
#pragma unroll
                for (int j = 0; j < 4; ++j)
                    acc[i][j] = fmaf(am[i], bn[j], acc[i][j]);
        }
    }
    float4 bb = make_float4(0.f, 0.f, 0.f, 0.f);
    if (bias) bb = *(const float4*)&bias[col0 + tx * 4];
#pragma unroll
    for (int i = 0; i < 4; ++i) {
        int r = row0 + ty * 4 + i;
        if (r < M) {
            float4 o;
            o.x = acc[i][0] + bb.x; o.y = acc[i][1] + bb.y;
            o.z = acc[i][2] + bb.z; o.w = acc[i][3] + bb.w;
            *(float4*)&C[r * ldc + col0 + tx * 4] = o;
        }
    }
}

extern "C" void kernel_launch(void* const* d_in, const int* in_sizes, int n_in,
                              void* d_out, int out_size, void* d_ws, size_t ws_size,
                              hipStream_t stream) {
    const float* x   = (const float*)d_in[0];
    const int*   ei  = (const int*)d_in[1];
    const float* W1  = (const float*)d_in[2];
    const float* b1  = (const float*)d_in[3];
    const float* Wmu = (const float*)d_in[4];
    const float* bmu = (const float*)d_in[5];
    const float* Wlv = (const float*)d_in[6];
    const float* blv = (const float*)d_in[7];
    const int* src = ei;
    const int* dst = ei + E_EDGES;

    float* H    = (float*)d_ws;               // [N,256]
    float* Z    = H + (size_t)N_NODES * D;    // [N,256]
    float* dinv = Z + (size_t)N_NODES * D;    // [N]
    int*   deg       = (int*)(dinv + N_NODES);
    int*   cursor    = deg + N_NODES;
    int*   row_start = cursor + N_NODES;      // [N+1]
    int*   csr_src   = row_start + N_NODES + 1;  // [E]
    float* Y  = H;                            // reuse H after gather1
    float* mu = (float*)d_out;
    float* lv = mu + (size_t)N_NODES * L;

    const int node_waves_blocks = (N_NODES + 3) / 4;  // 12500

    // CSR build (deg + cursor zeroed together: they are adjacent)
    zero_i<<<(2 * N_NODES + 255) / 256, 256, 0, stream>>>(deg, 2 * N_NODES);
    deg_count<<<(E_EDGES + 255) / 256, 256, 0, stream>>>(dst, deg);
    scan_rows<<<1, 1024, 0, stream>>>(deg, row_start);
    deg_fin<<<(N_NODES + 255) / 256, 256, 0, stream>>>(deg, dinv);
    fill_csr<<<(E_EDGES + 255) / 256, 256, 0, stream>>>(src, dst, row_start, cursor, csr_src);

    // layer 1: H = X@W1 ; Z = relu(P·H + b1)
    gemm_k256<<<dim3(782, 4), 256, 0, stream>>>(x, W1, D, nullptr, H, D, N_NODES);
    gather_csr<<<node_waves_blocks, 256, 0, stream>>>(H, Z, row_start, csr_src, dinv, b1, 1);

    // layer 2: Y = P·Z (aggregation commutes with the head matmuls)
    gather_csr<<<node_waves_blocks, 256, 0, stream>>>(Z, Y, row_start, csr_src, dinv, nullptr, 0);

    // heads
    gemm_k256<<<dim3(782, 2), 256, 0, stream>>>(Y, Wmu, L, bmu, mu, L, N_NODES);
    gemm_k256<<<dim3(782, 2), 256, 0, stream>>>(Y, Wlv, L, blv, lv, L, N_NODES);
}

// Round 3
// 453.850 us; speedup vs baseline: 12.5399x; 1.4209x over previous
//
#include <hip/hip_runtime.h>

#define N_NODES 50000
#define E_EDGES 800000
#define D 256
#define L 128
#define NB_SCAN 196   // ceil(N/256)

typedef __attribute__((ext_vector_type(8))) short bf16x8;
typedef __attribute__((ext_vector_type(4))) float f32x4;

__device__ __forceinline__ float bf2f(unsigned short u) {
    union { unsigned int i; float f; } v; v.i = ((unsigned int)u) << 16; return v.f;
}
__device__ __forceinline__ unsigned short f2bf(float f) {  // round-to-nearest-even
    union { float f; unsigned int i; } v; v.f = f;
    unsigned int r = v.i + 0x7fffu + ((v.i >> 16) & 1u);
    return (unsigned short)(r >> 16);
}

__global__ __launch_bounds__(256) void zero_i(int* __restrict__ p, int n) {
    int i = blockIdx.x * 256 + threadIdx.x;
    if (i < n) p[i] = 0;
}

__global__ __launch_bounds__(256) void deg_count(const int* __restrict__ dst,
                                                 int* __restrict__ deg) {
    int e = blockIdx.x * 256 + threadIdx.x;
    if (e < E_EDGES) atomicAdd(&deg[dst[e]], 1);
}

// ---- 3-phase parallel exclusive scan of deg -> row_start ----
__global__ __launch_bounds__(256) void scan_p1(const int* __restrict__ deg,
                                               int* __restrict__ bsum) {
    __shared__ int ws[4];
    int t = threadIdx.x, lane = t & 63, wid = t >> 6;
    int idx = blockIdx.x * 256 + t;
    int v = (idx < N_NODES) ? deg[idx] : 0;
#pragma unroll
    for (int off = 32; off; off >>= 1) v += __shfl_xor(v, off, 64);
    if (lane == 0) ws[wid] = v;
    __syncthreads();
    if (t == 0) bsum[blockIdx.x] = ws[0] + ws[1] + ws[2] + ws[3];
}

__global__ __launch_bounds__(256) void scan_p2(const int* __restrict__ bsum,
                                               int* __restrict__ bofs,
                                               int* __restrict__ row_start) {
    __shared__ int wsum[4], wofs[4];
    int t = threadIdx.x, lane = t & 63, wid = t >> 6;
    int v = (t < NB_SCAN) ? bsum[t] : 0;
    int s = v;
#pragma unroll
    for (int off = 1; off < 64; off <<= 1) {
        int x = __shfl_up(s, off, 64);
        if (lane >= off) s += x;
    }
    if (lane == 63) wsum[wid] = s;
    __syncthreads();
    if (t == 0) { int a = 0; for (int i = 0; i < 4; ++i) { wofs[i] = a; a += wsum[i]; } }
    __syncthreads();
    if (t < NB_SCAN) bofs[t] = wofs[wid] + s - v;
    if (t == 0) row_start[N_NODES] = E_EDGES;
}

__global__ __launch_bounds__(256) void scan_p3(const int* __restrict__ deg,
                                               const int* __restrict__ bofs,
                                               int* __restrict__ row_start,
                                               float* __restrict__ dinv) {
    __shared__ int wsum[4], wofs[4];
    int t = threadIdx.x, lane = t & 63, wid = t >> 6;
    int idx = blockIdx.x * 256 + t;
    int v = (idx < N_NODES) ? deg[idx] : 0;
    int s = v;
#pragma unroll
    for (int off = 1; off < 64; off <<= 1) {
        int x = __shfl_up(s, off, 64);
        if (lane >= off) s += x;
    }
    if (lane == 63) wsum[wid] = s;
    __syncthreads();
    if (t == 0) { int a = 0; for (int i = 0; i < 4; ++i) { wofs[i] = a; a += wsum[i]; } }
    __syncthreads();
    if (idx < N_NODES) {
        row_start[idx] = bofs[blockIdx.x] + wofs[wid] + s - v;
        dinv[idx] = rsqrtf((float)v + 1.0f);
    }
}

__global__ __launch_bounds__(256) void fill_csr(const int* __restrict__ src,
                                                const int* __restrict__ dst,
                                                const int* __restrict__ row_start,
                                                int* __restrict__ cursor,
                                                int* __restrict__ csr_src) {
    int e = blockIdx.x * 256 + threadIdx.x;
    if (e >= E_EDGES) return;
    int d = dst[e];
    int pos = atomicAdd(&cursor[d], 1);
    csr_src[row_start[d] + pos] = src[e];
}

// split fp32 -> bf16 hi + bf16 lo residual, 4 elems/thread
__global__ __launch_bounds__(256) void split_x(const float* __restrict__ x,
                                               unsigned short* __restrict__ xh,
                                               unsigned short* __restrict__ xl) {
    int i = blockIdx.x * 256 + threadIdx.x;
    if (i >= N_NODES * D / 4) return;
    float4 v = ((const float4*)x)[i];
    ushort4 h, l;
    h.x = f2bf(v.x); l.x = f2bf(v.x - bf2f(h.x));
    h.y = f2bf(v.y); l.y = f2bf(v.y - bf2f(h.y));
    h.z = f2bf(v.z); l.z = f2bf(v.z - bf2f(h.z));
    h.w = f2bf(v.w); l.w = f2bf(v.w - bf2f(h.w));
    ((ushort4*)xh)[i] = h;
    ((ushort4*)xl)[i] = l;
}

// Transpose + split weights into [n][k] bf16 hi/lo. Blocks 0..255: W1 (n=b, k=t).
// Blocks 256..511: Wcat = [Wmu | Wlv] (n=b-256, k=t). Block 256 also fills bcat.
__global__ __launch_bounds__(256) void prep_w(
    const float* __restrict__ W1, const float* __restrict__ Wmu,
    const float* __restrict__ Wlv, const float* __restrict__ bmu,
    const float* __restrict__ blv,
    unsigned short* __restrict__ W1h, unsigned short* __restrict__ W1l,
    unsigned short* __restrict__ Wch, unsigned short* __restrict__ Wcl,
    float* __restrict__ bcat) {
    int b = blockIdx.x, t = threadIdx.x;
    if (b < 256) {
        int n = b, k = t;
        float w = W1[k * 256 + n];
        unsigned short h = f2bf(w);
        W1h[n * 256 + k] = h;
        W1l[n * 256 + k] = f2bf(w - bf2f(h));
    } else {
        int n = b - 256, k = t;
        float w = (n < 128) ? Wmu[k * 128 + n] : Wlv[k * 128 + (n - 128)];
        unsigned short h = f2bf(w);
        Wch[n * 256 + k] = h;
        Wcl[n * 256 + k] = f2bf(w - bf2f(h));
        if (b == 256) bcat[t] = (t < 128) ? bmu[t] : blv[t - 128];
    }
}

// MFMA GEMM: C[M,256] = (Ah+Al)[M,256] @ (Bh+Bl)[256,256], fp32-split 3-term.
// A bf16 hi/lo row-major (k contig). Bt* are B transposed: [n][k] bf16 hi/lo.
// Block = 128 rows x 256 cols, 4 waves x 32 rows. A-frags direct from global
// (each element read exactly once); B staged in LDS with XOR swizzle (2-way, free).
// mode 0: store bf16 to Hout. mode 1: +bias, fp32 split store to mu/lv.
__global__ __launch_bounds__(256) void gemm_mfma(
    const unsigned short* __restrict__ Ah, const unsigned short* __restrict__ Al,
    const unsigned short* __restrict__ Bth, const unsigned short* __restrict__ Btl,
    unsigned short* __restrict__ Hout,
    float* __restrict__ mu, float* __restrict__ lv,
    const float* __restrict__ bias, int M, int mode)
{
    __shared__ unsigned short Bsh[256 * 32];
    __shared__ unsigned short Bsl[256 * 32];
    const int t = threadIdx.x;
    const int lane = t & 63, wave = t >> 6;
    const int row0 = blockIdx.x * 128 + wave * 32;
    const int m_ = lane & 15, q = lane >> 4;
    int rA0 = row0 + m_;      if (rA0 >= M) rA0 = M - 1;
    int rA1 = row0 + 16 + m_; if (rA1 >= M) rA1 = M - 1;
    const int bn = t >> 2;   // B staging: base row 0..63
    const int bc = t & 3;    // chunk 0..3

    f32x4 acc[2][16];
    const f32x4 zf = {0.f, 0.f, 0.f, 0.f};
#pragma unroll
    for (int mt = 0; mt < 2; ++mt)
#pragma unroll
        for (int nt = 0; nt < 16; ++nt) acc[mt][nt] = zf;

    for (int ks = 0; ks < 8; ++ks) {
        const int k0 = ks * 32;
        bf16x8 gbh[4], gbl[4];
#pragma unroll
        for (int i = 0; i < 4; ++i) {
            int n = bn + i * 64;
            gbh[i] = *(const bf16x8*)(Bth + n * 256 + k0 + bc * 8);
            gbl[i] = *(const bf16x8*)(Btl + n * 256 + k0 + bc * 8);
        }
        bf16x8 ah0 = *(const bf16x8*)(Ah + (size_t)rA0 * 256 + k0 + q * 8);
        bf16x8 al0 = *(const bf16x8*)(Al + (size_t)rA0 * 256 + k0 + q * 8);
        bf16x8 ah1 = *(const bf16x8*)(Ah + (size_t)rA1 * 256 + k0 + q * 8);
        bf16x8 al1 = *(const bf16x8*)(Al + (size_t)rA1 * 256 + k0 + q * 8);
        __syncthreads();
#pragma unroll
        for (int i = 0; i < 4; ++i) {
            int n = bn + i * 64;
            int cc = (bc ^ ((n >> 1) & 3)) * 8;
            *(bf16x8*)&Bsh[n * 32 + cc] = gbh[i];
            *(bf16x8*)&Bsl[n * 32 + cc] = gbl[i];
        }
        __syncthreads();
#pragma unroll
        for (int nt = 0; nt < 16; ++nt) {
            int n = nt * 16 + m_;
            int cr = (q ^ ((n >> 1) & 3)) * 8;
            bf16x8 bh = *(const bf16x8*)&Bsh[n * 32 + cr];
            bf16x8 bl = *(const bf16x8*)&Bsl[n * 32 + cr];
            acc[0][nt] = __builtin_amdgcn_mfma_f32_16x16x32_bf16(ah0, bh, acc[0][nt], 0, 0, 0);
            acc[1][nt] = __builtin_amdgcn_mfma_f32_16x16x32_bf16(ah1, bh, acc[1][nt], 0, 0, 0);
            acc[0][nt] = __builtin_amdgcn_mfma_f32_16x16x32_bf16(ah0, bl, acc[0][nt], 0, 0, 0);
            acc[1][nt] = __builtin_amdgcn_mfma_f32_16x16x32_bf16(ah1, bl, acc[1][nt], 0, 0, 0);
            acc[0][nt] = __builtin_amdgcn_mfma_f32_16x16x32_bf16(al0, bh, acc[0][nt], 0, 0, 0);
            acc[1][nt] = __builtin_amdgcn_mfma_f32_16x16x32_bf16(al1, bh, acc[1][nt], 0, 0, 0);
        }
    }
    // epilogue: C/D layout col=lane&15, row=(lane>>4)*4+reg  [m89/m91 verified]
#pragma unroll
    for (int mt = 0; mt < 2; ++mt) {
        int rbase = row0 + mt * 16 + q * 4;
#pragma unroll
        for (int r = 0; r < 4; ++r) {
            int grow = rbase + r;
            if (grow >= M) continue;
#pragma unroll
            for (int nt = 0; nt < 16; ++nt) {
                int gcol = nt * 16 + m_;
                float v = acc[mt][nt][r];
                if (mode == 0) {
                    Hout[(size_t)grow * 256 + gcol] = f2bf(v);
                } else {
                    v += bias[gcol];
                    if (gcol < 128) mu[(size_t)grow * 128 + gcol] = v;
                    else            lv[(size_t)grow * 128 + (gcol - 128)] = v;
                }
            }
        }
    }
}

// One wave per dst node over bf16 features; fp32 accumulate; fuses self-loop.
// mode 0: Z = relu(agg + bias) -> bf16. mode 1: Y -> bf16 hi/lo pair.
__global__ __launch_bounds__(256) void gather_bf16(
    const unsigned short* __restrict__ Hs,
    const int* __restrict__ row_start, const int* __restrict__ csr_src,
    const float* __restrict__ dinv, const float* __restrict__ bias,
    unsigned short* __restrict__ OutZ,
    unsigned short* __restrict__ OutYh, unsigned short* __restrict__ OutYl,
    int mode)
{
    int node = blockIdx.x * 4 + (threadIdx.x >> 6);
    if (node >= N_NODES) return;
    int lane = threadIdx.x & 63;
    const int col = lane * 4;
    int beg = row_start[node], end = row_start[node + 1];
    float dn = dinv[node];
    float a0 = 0.f, a1 = 0.f, a2 = 0.f, a3 = 0.f;
    int i = beg;
    for (; i + 1 < end; i += 2) {
        int s0 = csr_src[i], s1 = csr_src[i + 1];
        float w0 = dinv[s0] * dn, w1 = dinv[s1] * dn;
        ushort4 u0 = *(const ushort4*)(Hs + (size_t)s0 * D + col);
        ushort4 u1 = *(const ushort4*)(Hs + (size_t)s1 * D + col);
        a0 = fmaf(bf2f(u1.x), w1, fmaf(bf2f(u0.x), w0, a0));
        a1 = fmaf(bf2f(u1.y), w1, fmaf(bf2f(u0.y), w0, a1));
        a2 = fmaf(bf2f(u1.z), w1, fmaf(bf2f(u0.z), w0, a2));
        a3 = fmaf(bf2f(u1.w), w1, fmaf(bf2f(u0.w), w0, a3));
    }
    if (i < end) {
        int s0 = csr_src[i];
        float w0 = dinv[s0] * dn;
        ushort4 u0 = *(const ushort4*)(Hs + (size_t)s0 * D + col);
        a0 = fmaf(bf2f(u0.x), w0, a0);
        a1 = fmaf(bf2f(u0.y), w0, a1);
        a2 = fmaf(bf2f(u0.z), w0, a2);
        a3 = fmaf(bf2f(u0.w), w0, a3);
    }
    float sl = dn * dn;  // self-loop norm 1/deg
    ushort4 h = *(const ushort4*)(Hs + (size_t)node * D + col);
    a0 = fmaf(bf2f(h.x), sl, a0);
    a1 = fmaf(bf2f(h.y), sl, a1);
    a2 = fmaf(bf2f(h.z), sl, a2);
    a3 = fmaf(bf2f(h.w), sl, a3);
    if (mode == 0) {
        a0 = fmaxf(a0 + bias[col + 0], 0.f);
        a1 = fmaxf(a1 + bias[col + 1], 0.f);
        a2 = fmaxf(a2 + bias[col + 2], 0.f);
        a3 = fmaxf(a3 + bias[col + 3], 0.f);
        ushort4 o; o.x = f2bf(a0); o.y = f2bf(a1); o.z = f2bf(a2); o.w = f2bf(a3);
        *(ushort4*)(OutZ + (size_t)node * D + col) = o;
    } else {
        ushort4 oh, ol;
        oh.x = f2bf(a0); ol.x = f2bf(a0 - bf2f(oh.x));
        oh.y = f2bf(a1); ol.y = f2bf(a1 - bf2f(oh.y));
        oh.z = f2bf(a2); ol.z = f2bf(a2 - bf2f(oh.z));
        oh.w = f2bf(a3); ol.w = f2bf(a3 - bf2f(oh.w));
        *(ushort4*)(OutYh + (size_t)node * D + col) = oh;
        *(ushort4*)(OutYl + (size_t)node * D + col) = ol;
    }
}

extern "C" void kernel_launch(void* const* d_in, const int* in_sizes, int n_in,
                              void* d_out, int out_size, void* d_ws, size_t ws_size,
                              hipStream_t stream) {
    const float* x   = (const float*)d_in[0];
    const int*   ei  = (const int*)d_in[1];
    const float* W1  = (const float*)d_in[2];
    const float* b1  = (const float*)d_in[3];
    const float* Wmu = (const float*)d_in[4];
    const float* bmu = (const float*)d_in[5];
    const float* Wlv = (const float*)d_in[6];
    const float* blv = (const float*)d_in[7];
    const int* src = ei;
    const int* dst = ei + E_EDGES;

    const size_t NF = (size_t)N_NODES * D;  // 12.8M
    unsigned short* Xh  = (unsigned short*)d_ws;
    unsigned short* Xl  = Xh + NF;
    unsigned short* Hb  = Xl + NF;
    unsigned short* W1h = Hb + NF;
    unsigned short* W1l = W1h + 65536;
    unsigned short* Wch = W1l + 65536;
    unsigned short* Wcl = Wch + 65536;
    float* bcat = (float*)(Wcl + 65536);
    float* dinv = bcat + 256;
    int* deg       = (int*)(dinv + N_NODES);
    int* cursor    = deg + N_NODES;
    int* row_start = cursor + N_NODES;       // N+1
    int* bsum      = row_start + N_NODES + 1;
    int* bofs      = bsum + NB_SCAN;
    int* csr_src   = bofs + NB_SCAN;         // E
    unsigned short* Z  = Xh;  // Xh dead after gemm1
    unsigned short* Yh = Xl;  // Xl dead after gemm1
    unsigned short* Yl = Hb;  // Hb dead after gather1
    float* mu = (float*)d_out;
    float* lv = mu + (size_t)N_NODES * L;

    // CSR build + norms
    zero_i<<<(2 * N_NODES + 255) / 256, 256, 0, stream>>>(deg, 2 * N_NODES);
    deg_count<<<(E_EDGES + 255) / 256, 256, 0, stream>>>(dst, deg);
    scan_p1<<<NB_SCAN, 256, 0, stream>>>(deg, bsum);
    scan_p2<<<1, 256, 0, stream>>>(bsum, bofs, row_start);
    scan_p3<<<NB_SCAN, 256, 0, stream>>>(deg, bofs, row_start, dinv);
    fill_csr<<<(E_EDGES + 255) / 256, 256, 0, stream>>>(src, dst, row_start, cursor, csr_src);

    // operand prep
    split_x<<<(int)(NF / 4 + 255) / 256, 256, 0, stream>>>(x, Xh, Xl);
    prep_w<<<512, 256, 0, stream>>>(W1, Wmu, Wlv, bmu, blv, W1h, W1l, Wch, Wcl, bcat);

    const int gemm_blocks = (N_NODES + 127) / 128;  // 391
    // layer 1: H = X@W1 (bf16 out)
    gemm_mfma<<<gemm_blocks, 256, 0, stream>>>(Xh, Xl, W1h, W1l, Hb,
                                               nullptr, nullptr, nullptr, N_NODES, 0);
    // Z = relu(P·H + b1) (bf16)
    gather_bf16<<<(N_NODES + 3) / 4, 256, 0, stream>>>(Hb, row_start, csr_src, dinv, b1,
                                                       Z, nullptr, nullptr, 0);
    // Y = P·Z (bf16 hi/lo)
    gather_bf16<<<(N_NODES + 3) / 4, 256, 0, stream>>>(Z, row_start, csr_src, dinv, nullptr,
                                                       nullptr, Yh, Yl, 1);
    // heads: [mu|lv] = Y@[Wmu|Wlv] + [bmu|blv] (fp32 out)
    gemm_mfma<<<gemm_blocks, 256, 0, stream>>>(Yh, Yl, Wch, Wcl, nullptr,
                                               mu, lv, bcat, N_NODES, 1);
}

// Round 4
// 398.640 us; speedup vs baseline: 14.2767x; 1.1385x over previous
//
#include <hip/hip_runtime.h>

#define N_NODES 50000
#define E_EDGES 800000
#define D 256
#define L 128
#define NB_SCAN 196   // ceil(N/256)

typedef __attribute__((ext_vector_type(8))) short bf16x8;
typedef __attribute__((ext_vector_type(4))) float f32x4;

__device__ __forceinline__ float bf2f(unsigned short u) {
    union { unsigned int i; float f; } v; v.i = ((unsigned int)u) << 16; return v.f;
}
__device__ __forceinline__ unsigned short f2bf(float f) {  // round-to-nearest-even
    union { float f; unsigned int i; } v; v.f = f;
    unsigned int r = v.i + 0x7fffu + ((v.i >> 16) & 1u);
    return (unsigned short)(r >> 16);
}

__global__ __launch_bounds__(256) void zero_i(int* __restrict__ p, int n) {
    int i = blockIdx.x * 256 + threadIdx.x;
    if (i < n) p[i] = 0;
}

__global__ __launch_bounds__(256) void deg_count(const int* __restrict__ dst,
                                                 int* __restrict__ deg) {
    int e = blockIdx.x * 256 + threadIdx.x;
    if (e < E_EDGES) atomicAdd(&deg[dst[e]], 1);
}

// ---- 3-phase parallel exclusive scan of deg -> row_start ----
__global__ __launch_bounds__(256) void scan_p1(const int* __restrict__ deg,
                                               int* __restrict__ bsum) {
    __shared__ int ws[4];
    int t = threadIdx.x, lane = t & 63, wid = t >> 6;
    int idx = blockIdx.x * 256 + t;
    int v = (idx < N_NODES) ? deg[idx] : 0;
#pragma unroll
    for (int off = 32; off; off >>= 1) v += __shfl_xor(v, off, 64);
    if (lane == 0) ws[wid] = v;
    __syncthreads();
    if (t == 0) bsum[blockIdx.x] = ws[0] + ws[1] + ws[2] + ws[3];
}

__global__ __launch_bounds__(256) void scan_p2(const int* __restrict__ bsum,
                                               int* __restrict__ bofs,
                                               int* __restrict__ row_start) {
    __shared__ int wsum[4], wofs[4];
    int t = threadIdx.x, lane = t & 63, wid = t >> 6;
    int v = (t < NB_SCAN) ? bsum[t] : 0;
    int s = v;
#pragma unroll
    for (int off = 1; off < 64; off <<= 1) {
        int x = __shfl_up(s, off, 64);
        if (lane >= off) s += x;
    }
    if (lane == 63) wsum[wid] = s;
    __syncthreads();
    if (t == 0) { int a = 0; for (int i = 0; i < 4; ++i) { wofs[i] = a; a += wsum[i]; } }
    __syncthreads();
    if (t < NB_SCAN) bofs[t] = wofs[wid] + s - v;
    if (t == 0) row_start[N_NODES] = E_EDGES;
}

__global__ __launch_bounds__(256) void scan_p3(const int* __restrict__ deg,
                                               const int* __restrict__ bofs,
                                               int* __restrict__ row_start,
                                               float* __restrict__ dinv) {
    __shared__ int wsum[4], wofs[4];
    int t = threadIdx.x, lane = t & 63, wid = t >> 6;
    int idx = blockIdx.x * 256 + t;
    int v = (idx < N_NODES) ? deg[idx] : 0;
    int s = v;
#pragma unroll
    for (int off = 1; off < 64; off <<= 1) {
        int x = __shfl_up(s, off, 64);
        if (lane >= off) s += x;
    }
    if (lane == 63) wsum[wid] = s;
    __syncthreads();
    if (t == 0) { int a = 0; for (int i = 0; i < 4; ++i) { wofs[i] = a; a += wsum[i]; } }
    __syncthreads();
    if (idx < N_NODES) {
        row_start[idx] = bofs[blockIdx.x] + wofs[wid] + s - v;
        dinv[idx] = rsqrtf((float)v + 1.0f);
    }
}

__global__ __launch_bounds__(256) void fill_csr(const int* __restrict__ src,
                                                const int* __restrict__ dst,
                                                const int* __restrict__ row_start,
                                                int* __restrict__ cursor,
                                                int* __restrict__ csr_src) {
    int e = blockIdx.x * 256 + threadIdx.x;
    if (e >= E_EDGES) return;
    int d = dst[e];
    int pos = atomicAdd(&cursor[d], 1);
    csr_src[row_start[d] + pos] = src[e];
}

// Transpose + split weights into [n][k] bf16 hi/lo. Blocks 0..255: W1 (n=b, k=t).
// Blocks 256..511: Wcat = [Wmu | Wlv] (n=b-256, k=t). Block 256 also fills bcat.
__global__ __launch_bounds__(256) void prep_w(
    const float* __restrict__ W1, const float* __restrict__ Wmu,
    const float* __restrict__ Wlv, const float* __restrict__ bmu,
    const float* __restrict__ blv,
    unsigned short* __restrict__ W1h, unsigned short* __restrict__ W1l,
    unsigned short* __restrict__ Wch, unsigned short* __restrict__ Wcl,
    float* __restrict__ bcat) {
    int b = blockIdx.x, t = threadIdx.x;
    if (b < 256) {
        int n = b, k = t;
        float w = W1[k * 256 + n];
        unsigned short h = f2bf(w);
        W1h[n * 256 + k] = h;
        W1l[n * 256 + k] = f2bf(w - bf2f(h));
    } else {
        int n = b - 256, k = t;
        float w = (n < 128) ? Wmu[k * 128 + n] : Wlv[k * 128 + (n - 128)];
        unsigned short h = f2bf(w);
        Wch[n * 256 + k] = h;
        Wcl[n * 256 + k] = f2bf(w - bf2f(h));
        if (b == 256) bcat[t] = (t < 128) ? bmu[t] : blv[t - 128];
    }
}

// MFMA GEMM: C[M,256] = A_f32[M,256] @ (Bh+Bl)[256,256], fp32-split 3-term.
// A fp32 row-major, split to bf16 hi/lo IN-REGISTER. Bt* transposed [n][k] bf16.
// Block = 64 rows x 256 cols, 4 waves x 16 rows -> grid 782 (3 blocks/CU).
// B staged in LDS, XOR-swizzled (2-way aliasing only = free).
// mode 0: store bf16 to Hout. mode 1: +bias, fp32 store to mu/lv.
__global__ __launch_bounds__(256, 3) void gemm_mfma(
    const float* __restrict__ A,
    const unsigned short* __restrict__ Bth, const unsigned short* __restrict__ Btl,
    unsigned short* __restrict__ Hout,
    float* __restrict__ mu, float* __restrict__ lv,
    const float* __restrict__ bias, int M, int mode)
{
    __shared__ unsigned short Bsh[256 * 32];
    __shared__ unsigned short Bsl[256 * 32];
    const int t = threadIdx.x;
    const int lane = t & 63, wave = t >> 6;
    const int row0 = blockIdx.x * 64 + wave * 16;
    const int m_ = lane & 15, q = lane >> 4;
    int rA = row0 + m_; if (rA >= M) rA = M - 1;
    const float* Ap = A + (size_t)rA * 256;
    const int bn = t >> 2;   // B staging: base row 0..63
    const int bc = t & 3;    // chunk 0..3

    f32x4 acc[16];
    const f32x4 zf = {0.f, 0.f, 0.f, 0.f};
#pragma unroll
    for (int nt = 0; nt < 16; ++nt) acc[nt] = zf;

    for (int ks = 0; ks < 8; ++ks) {
        const int k0 = ks * 32;
        bf16x8 gbh[4], gbl[4];
#pragma unroll
        for (int i = 0; i < 4; ++i) {
            int n = bn + i * 64;
            gbh[i] = *(const bf16x8*)(Bth + n * 256 + k0 + bc * 8);
            gbl[i] = *(const bf16x8*)(Btl + n * 256 + k0 + bc * 8);
        }
        float4 av0 = *(const float4*)(Ap + k0 + q * 8);
        float4 av1 = *(const float4*)(Ap + k0 + q * 8 + 4);
        __syncthreads();
#pragma unroll
        for (int i = 0; i < 4; ++i) {
            int n = bn + i * 64;
            int cc = (bc ^ ((n >> 1) & 3)) * 8;
            *(bf16x8*)&Bsh[n * 32 + cc] = gbh[i];
            *(bf16x8*)&Bsl[n * 32 + cc] = gbl[i];
        }
        // in-register fp32 -> bf16 hi/lo split of the A fragment
        float af[8] = {av0.x, av0.y, av0.z, av0.w, av1.x, av1.y, av1.z, av1.w};
        bf16x8 ah, al;
#pragma unroll
        for (int j = 0; j < 8; ++j) {
            unsigned short h = f2bf(af[j]);
            ah[j] = (short)h;
            al[j] = (short)f2bf(af[j] - bf2f(h));
        }
        __syncthreads();
#pragma unroll
        for (int nt = 0; nt < 16; ++nt) {
            int n = nt * 16 + m_;
            int cr = (q ^ ((n >> 1) & 3)) * 8;
            bf16x8 bh = *(const bf16x8*)&Bsh[n * 32 + cr];
            bf16x8 bl = *(const bf16x8*)&Bsl[n * 32 + cr];
            acc[nt] = __builtin_amdgcn_mfma_f32_16x16x32_bf16(ah, bh, acc[nt], 0, 0, 0);
            acc[nt] = __builtin_amdgcn_mfma_f32_16x16x32_bf16(ah, bl, acc[nt], 0, 0, 0);
            acc[nt] = __builtin_amdgcn_mfma_f32_16x16x32_bf16(al, bh, acc[nt], 0, 0, 0);
        }
    }
    // epilogue: C/D layout col=lane&15, row=(lane>>4)*4+reg  [m89/m91 verified]
    int rbase = row0 + q * 4;
#pragma unroll
    for (int r = 0; r < 4; ++r) {
        int grow = rbase + r;
        if (grow >= M) continue;
#pragma unroll
        for (int nt = 0; nt < 16; ++nt) {
            int gcol = nt * 16 + m_;
            float v = acc[nt][r];
            if (mode == 0) {
                Hout[(size_t)grow * 256 + gcol] = f2bf(v);
            } else {
                v += bias[gcol];
                if (gcol < 128) mu[(size_t)grow * 128 + gcol] = v;
                else            lv[(size_t)grow * 128 + (gcol - 128)] = v;
            }
        }
    }
}

// One wave per dst node over bf16 features; fp32 accumulate; fuses self-loop.
// mode 0: Z = relu(agg + bias) -> bf16. mode 1: Y -> fp32.
__global__ __launch_bounds__(256) void gather_bf16(
    const unsigned short* __restrict__ Hs,
    const int* __restrict__ row_start, const int* __restrict__ csr_src,
    const float* __restrict__ dinv, const float* __restrict__ bias,
    unsigned short* __restrict__ OutZ, float* __restrict__ OutY, int mode)
{
    int node = blockIdx.x * 4 + (threadIdx.x >> 6);
    if (node >= N_NODES) return;
    int lane = threadIdx.x & 63;
    const int col = lane * 4;
    int beg = row_start[node], end = row_start[node + 1];
    float dn = dinv[node];
    float a0 = 0.f, a1 = 0.f, a2 = 0.f, a3 = 0.f;
    int i = beg;
    for (; i + 1 < end; i += 2) {
        int s0 = csr_src[i], s1 = csr_src[i + 1];
        float w0 = dinv[s0] * dn, w1 = dinv[s1] * dn;
        ushort4 u0 = *(const ushort4*)(Hs + (size_t)s0 * D + col);
        ushort4 u1 = *(const ushort4*)(Hs + (size_t)s1 * D + col);
        a0 = fmaf(bf2f(u1.x), w1, fmaf(bf2f(u0.x), w0, a0));
        a1 = fmaf(bf2f(u1.y), w1, fmaf(bf2f(u0.y), w0, a1));
        a2 = fmaf(bf2f(u1.z), w1, fmaf(bf2f(u0.z), w0, a2));
        a3 = fmaf(bf2f(u1.w), w1, fmaf(bf2f(u0.w), w0, a3));
    }
    if (i < end) {
        int s0 = csr_src[i];
        float w0 = dinv[s0] * dn;
        ushort4 u0 = *(const ushort4*)(Hs + (size_t)s0 * D + col);
        a0 = fmaf(bf2f(u0.x), w0, a0);
        a1 = fmaf(bf2f(u0.y), w0, a1);
        a2 = fmaf(bf2f(u0.z), w0, a2);
        a3 = fmaf(bf2f(u0.w), w0, a3);
    }
    float sl = dn * dn;  // self-loop norm 1/deg
    ushort4 h = *(const ushort4*)(Hs + (size_t)node * D + col);
    a0 = fmaf(bf2f(h.x), sl, a0);
    a1 = fmaf(bf2f(h.y), sl, a1);
    a2 = fmaf(bf2f(h.z), sl, a2);
    a3 = fmaf(bf2f(h.w), sl, a3);
    if (mode == 0) {
        a0 = fmaxf(a0 + bias[col + 0], 0.f);
        a1 = fmaxf(a1 + bias[col + 1], 0.f);
        a2 = fmaxf(a2 + bias[col + 2], 0.f);
        a3 = fmaxf(a3 + bias[col + 3], 0.f);
        ushort4 o; o.x = f2bf(a0); o.y = f2bf(a1); o.z = f2bf(a2); o.w = f2bf(a3);
        *(ushort4*)(OutZ + (size_t)node * D + col) = o;
    } else {
        float4 o; o.x = a0; o.y = a1; o.z = a2; o.w = a3;
        *(float4*)(OutY + (size_t)node * D + col) = o;
    }
}

extern "C" void kernel_launch(void* const* d_in, const int* in_sizes, int n_in,
                              void* d_out, int out_size, void* d_ws, size_t ws_size,
                              hipStream_t stream) {
    const float* x   = (const float*)d_in[0];
    const int*   ei  = (const int*)d_in[1];
    const float* W1  = (const float*)d_in[2];
    const float* b1  = (const float*)d_in[3];
    const float* Wmu = (const float*)d_in[4];
    const float* bmu = (const float*)d_in[5];
    const float* Wlv = (const float*)d_in[6];
    const float* blv = (const float*)d_in[7];
    const int* src = ei;
    const int* dst = ei + E_EDGES;

    const size_t NF = (size_t)N_NODES * D;  // 12.8M
    unsigned short* Hb = (unsigned short*)d_ws;   // [N,256] bf16
    unsigned short* Z  = Hb + NF;                 // [N,256] bf16
    float* Y = (float*)(Z + NF);                  // [N,256] fp32
    unsigned short* W1h = (unsigned short*)(Y + NF);
    unsigned short* W1l = W1h + 65536;
    unsigned short* Wch = W1l + 65536;
    unsigned short* Wcl = Wch + 65536;
    float* bcat = (float*)(Wcl + 65536);
    float* dinv = bcat + 256;
    int* deg       = (int*)(dinv + N_NODES);
    int* cursor    = deg + N_NODES;
    int* row_start = cursor + N_NODES;       // N+1
    int* bsum      = row_start + N_NODES + 1;
    int* bofs      = bsum + NB_SCAN;
    int* csr_src   = bofs + NB_SCAN;         // E
    float* mu = (float*)d_out;
    float* lv = mu + (size_t)N_NODES * L;

    // CSR build + norms
    zero_i<<<(2 * N_NODES + 255) / 256, 256, 0, stream>>>(deg, 2 * N_NODES);
    deg_count<<<(E_EDGES + 255) / 256, 256, 0, stream>>>(dst, deg);
    scan_p1<<<NB_SCAN, 256, 0, stream>>>(deg, bsum);
    scan_p2<<<1, 256, 0, stream>>>(bsum, bofs, row_start);
    scan_p3<<<NB_SCAN, 256, 0, stream>>>(deg, bofs, row_start, dinv);
    fill_csr<<<(E_EDGES + 255) / 256, 256, 0, stream>>>(src, dst, row_start, cursor, csr_src);

    // weight prep
    prep_w<<<512, 256, 0, stream>>>(W1, Wmu, Wlv, bmu, blv, W1h, W1l, Wch, Wcl, bcat);

    const int gemm_blocks = (N_NODES + 63) / 64;  // 782
    // layer 1: H = X@W1 (bf16 out), fp32 A split in-register
    gemm_mfma<<<gemm_blocks, 256, 0, stream>>>(x, W1h, W1l, Hb,
                                               nullptr, nullptr, nullptr, N_NODES, 0);
    // Z = relu(P·H + b1) (bf16)
    gather_bf16<<<(N_NODES + 3) / 4, 256, 0, stream>>>(Hb, row_start, csr_src, dinv, b1,
                                                       Z, nullptr, 0);
    // Y = P·Z (fp32)
    gather_bf16<<<(N_NODES + 3) / 4, 256, 0, stream>>>(Z, row_start, csr_src, dinv, nullptr,
                                                       nullptr, Y, 1);
    // heads: [mu|lv] = Y@[Wmu|Wlv] + [bmu|blv] (fp32 out)
    gemm_mfma<<<gemm_blocks, 256, 0, stream>>>(Y, Wch, Wcl, nullptr,
                                               mu, lv, bcat, N_NODES, 1);
}